// Round 1
// baseline (1007.618 us; speedup 1.0000x reference)
//
#include <hip/hip_runtime.h>
#include <hip/hip_bf16.h>
#include <cstdint>

// SpatialAttention: B=8, C=256, CO=128, H=W=64, N=4096
//   q = Wq@p + bq   [B,N,CO]
//   k = Wk@b + bk   [B,N(CO-major)]
//   e = q k^T       [B,N,N]   (K=CO=128)  -- split-bf16 MFMA (fp32-accurate)
//   attn = softmax(e, -1)      (output 1)
//   out = attn @ b^T [B,C,N]   (output 0) -- bf16 MFMA
//
// d_ws layout (needs 50,331,648 bytes):
//   qhi/qlo/khi/klo: 4 x [8*4096*128] bf16, then Vb: [8*256*4096] bf16

#define BATCH 8
#define CCH   256
#define COO   128
#define NPIX  4096

typedef __bf16 bf16x8 __attribute__((ext_vector_type(8)));
typedef float  f32x4  __attribute__((ext_vector_type(4)));

// ---------------- K1: projection, fp32 compute, bf16 hi/lo split output [B][N][CO]
__global__ __launch_bounds__(256) void proj_kernel(
    const float* __restrict__ X,    // [B][C][N]
    const float* __restrict__ W,    // [CO][C]
    const float* __restrict__ bias, // [CO]
    __bf16* __restrict__ out_hi,    // [B][N][CO]
    __bf16* __restrict__ out_lo)
{
  __shared__ float wlds[16][256];
  __shared__ float blds[16];
  const int b   = blockIdx.z;
  const int o0  = blockIdx.y * 16;
  const int n0  = blockIdx.x * 1024;
  const int tid = threadIdx.x;

  for (int i = tid; i < 16 * 256; i += 256)
    wlds[i >> 8][i & 255] = W[(size_t)(o0 + (i >> 8)) * CCH + (i & 255)];
  if (tid < 16) blds[tid] = bias[o0 + tid];
  __syncthreads();

  const int n = n0 + tid * 4;
  const float* xp = X + ((size_t)b * CCH) * NPIX + n;

  float acc[16][4];
#pragma unroll
  for (int o = 0; o < 16; ++o)
#pragma unroll
    for (int j = 0; j < 4; ++j) acc[o][j] = 0.f;

  for (int c4 = 0; c4 < CCH; c4 += 4) {
    float pvv[4][4];
#pragma unroll
    for (int cc = 0; cc < 4; ++cc) {
      float4 t = *reinterpret_cast<const float4*>(xp + (size_t)(c4 + cc) * NPIX);
      pvv[cc][0] = t.x; pvv[cc][1] = t.y; pvv[cc][2] = t.z; pvv[cc][3] = t.w;
    }
#pragma unroll
    for (int o = 0; o < 16; ++o) {
      float4 wv = *reinterpret_cast<const float4*>(&wlds[o][c4]);
      float wa[4] = {wv.x, wv.y, wv.z, wv.w};
#pragma unroll
      for (int cc = 0; cc < 4; ++cc)
#pragma unroll
        for (int j = 0; j < 4; ++j)
          acc[o][j] += wa[cc] * pvv[cc][j];
    }
  }

#pragma unroll
  for (int j = 0; j < 4; ++j) {
    const size_t base = ((size_t)b * NPIX + n + j) * COO + o0;
    bf16x8 hv[2], lv[2];
#pragma unroll
    for (int o = 0; o < 16; ++o) {
      float v = acc[o][j] + blds[o];
      __bf16 h = (__bf16)v;
      float  r = v - (float)h;
      hv[o >> 3][o & 7] = h;
      lv[o >> 3][o & 7] = (__bf16)r;
    }
    *reinterpret_cast<bf16x8*>(out_hi + base)     = hv[0];
    *reinterpret_cast<bf16x8*>(out_hi + base + 8) = hv[1];
    *reinterpret_cast<bf16x8*>(out_lo + base)     = lv[0];
    *reinterpret_cast<bf16x8*>(out_lo + base + 8) = lv[1];
  }
}

// ---------------- K1b: f32 -> bf16 elementwise (V copy)
__global__ __launch_bounds__(256) void cvt_bf16_kernel(
    const float* __restrict__ in, __bf16* __restrict__ outp, int n8)
{
  const int idx = blockIdx.x * 256 + threadIdx.x;
  if (idx >= n8) return;
  const float* ip = in + (size_t)idx * 8;
  float4 x = *reinterpret_cast<const float4*>(ip);
  float4 y = *reinterpret_cast<const float4*>(ip + 4);
  bf16x8 t;
  t[0] = (__bf16)x.x; t[1] = (__bf16)x.y; t[2] = (__bf16)x.z; t[3] = (__bf16)x.w;
  t[4] = (__bf16)y.x; t[5] = (__bf16)y.y; t[6] = (__bf16)y.z; t[7] = (__bf16)y.w;
  *reinterpret_cast<bf16x8*>(outp + (size_t)idx * 8) = t;
}

// ---------------- K2: energy e[n,m] = sum_o q[n,o]*k[m,o], split-bf16 (hi*hi+hi*lo+lo*hi)
// 128x128 tile per WG, 4 waves of 64x64, fragments loaded straight from global.
__global__ __launch_bounds__(256) void energy_kernel(
    const __bf16* __restrict__ qhip, const __bf16* __restrict__ qlop,
    const __bf16* __restrict__ khip, const __bf16* __restrict__ klop,
    float* __restrict__ eout)
{
  const int b   = blockIdx.z;
  const int m0  = blockIdx.x * 128;
  const int n0  = blockIdx.y * 128;
  const int tid = threadIdx.x;
  const int w = tid >> 6, l = tid & 63;
  const int wr = w >> 1, wc = w & 1;
  const int rl = l & 15;
  const int k8 = (l >> 4) * 8;

  const size_t qrow = ((size_t)b * NPIX + n0 + wr * 64 + rl) * COO + k8;
  const size_t krow = ((size_t)b * NPIX + m0 + wc * 64 + rl) * COO + k8;
  const __bf16* qhp = qhip + qrow;
  const __bf16* qlp = qlop + qrow;
  const __bf16* khp = khip + krow;
  const __bf16* klp = klop + krow;

  f32x4 zero = {0.f, 0.f, 0.f, 0.f};
  f32x4 acc[4][4];
#pragma unroll
  for (int fr = 0; fr < 4; ++fr)
#pragma unroll
    for (int fc = 0; fc < 4; ++fc) acc[fr][fc] = zero;

#pragma unroll
  for (int ks = 0; ks < 4; ++ks) {
    const int ko = ks * 32;
    bf16x8 ah[4], al[4], bh[4], bl[4];
#pragma unroll
    for (int f = 0; f < 4; ++f) {
      const size_t off = (size_t)f * 16 * COO + ko;
      ah[f] = *reinterpret_cast<const bf16x8*>(qhp + off);
      al[f] = *reinterpret_cast<const bf16x8*>(qlp + off);
      bh[f] = *reinterpret_cast<const bf16x8*>(khp + off);
      bl[f] = *reinterpret_cast<const bf16x8*>(klp + off);
    }
#pragma unroll
    for (int fr = 0; fr < 4; ++fr)
#pragma unroll
      for (int fc = 0; fc < 4; ++fc) {
        acc[fr][fc] = __builtin_amdgcn_mfma_f32_16x16x32_bf16(ah[fr], bh[fc], acc[fr][fc], 0, 0, 0);
        acc[fr][fc] = __builtin_amdgcn_mfma_f32_16x16x32_bf16(ah[fr], bl[fc], acc[fr][fc], 0, 0, 0);
        acc[fr][fc] = __builtin_amdgcn_mfma_f32_16x16x32_bf16(al[fr], bh[fc], acc[fr][fc], 0, 0, 0);
      }
  }

  const int cg = (l >> 4) * 4;
#pragma unroll
  for (int fr = 0; fr < 4; ++fr)
#pragma unroll
    for (int r = 0; r < 4; ++r) {
      const int row = n0 + wr * 64 + fr * 16 + cg + r;
      float* op = eout + ((size_t)b * NPIX + row) * NPIX + m0 + wc * 64 + rl;
#pragma unroll
      for (int fc = 0; fc < 4; ++fc)
        op[fc * 16] = acc[fr][fc][r];
    }
}

// ---------------- K3: row softmax in place, one WG (256t) per row, row register-resident
__global__ __launch_bounds__(256) void softmax_kernel(float* __restrict__ attn)
{
  const size_t row = blockIdx.x;
  float* p = attn + row * NPIX;
  const int tid = threadIdx.x;
  const int w = tid >> 6, l = tid & 63;

  float4 v[4];
#pragma unroll
  for (int j = 0; j < 4; ++j)
    v[j] = *reinterpret_cast<const float4*>(p + j * 1024 + tid * 4);

  float m = -1e30f;
#pragma unroll
  for (int j = 0; j < 4; ++j) {
    m = fmaxf(m, fmaxf(fmaxf(v[j].x, v[j].y), fmaxf(v[j].z, v[j].w)));
  }
#pragma unroll
  for (int off = 32; off; off >>= 1) m = fmaxf(m, __shfl_xor(m, off));

  __shared__ float smax[4];
  __shared__ float ssum[4];
  if (l == 0) smax[w] = m;
  __syncthreads();
  m = fmaxf(fmaxf(smax[0], smax[1]), fmaxf(smax[2], smax[3]));

  float s = 0.f;
#pragma unroll
  for (int j = 0; j < 4; ++j) {
    v[j].x = __expf(v[j].x - m); s += v[j].x;
    v[j].y = __expf(v[j].y - m); s += v[j].y;
    v[j].z = __expf(v[j].z - m); s += v[j].z;
    v[j].w = __expf(v[j].w - m); s += v[j].w;
  }
#pragma unroll
  for (int off = 32; off; off >>= 1) s += __shfl_xor(s, off);
  if (l == 0) ssum[w] = s;
  __syncthreads();
  s = ssum[0] + ssum[1] + ssum[2] + ssum[3];
  const float inv = 1.0f / s;

#pragma unroll
  for (int j = 0; j < 4; ++j) {
    v[j].x *= inv; v[j].y *= inv; v[j].z *= inv; v[j].w *= inv;
    *reinterpret_cast<float4*>(p + j * 1024 + tid * 4) = v[j];
  }
}

// ---------------- K4: out[c,n] = sum_m V[c,m] * attn[n,m]; 256c x 64n per WG
__global__ __launch_bounds__(256) void pv_kernel(
    const __bf16* __restrict__ V,    // [B][C][M] bf16
    const float*  __restrict__ attn, // [B][N][M] f32
    float* __restrict__ out)         // [B][C][N]
{
  const int b   = blockIdx.z;
  const int n0  = blockIdx.x * 64;
  const int tid = threadIdx.x;
  const int w = tid >> 6, l = tid & 63;
  const int wr = w >> 1, wc = w & 1;
  const int rl = l & 15, k8 = (l >> 4) * 8;

  const __bf16* vp = V + ((size_t)b * CCH + wr * 128 + rl) * NPIX + k8;
  const float*  ap = attn + ((size_t)b * NPIX + n0 + wc * 32 + rl) * NPIX + k8;

  f32x4 zero = {0.f, 0.f, 0.f, 0.f};
  f32x4 acc[8][2];
#pragma unroll
  for (int fr = 0; fr < 8; ++fr) { acc[fr][0] = zero; acc[fr][1] = zero; }

  for (int ks = 0; ks < 128; ++ks) {
    const int mo = ks * 32;
    bf16x8 a[8];
#pragma unroll
    for (int f = 0; f < 8; ++f)
      a[f] = *reinterpret_cast<const bf16x8*>(vp + (size_t)f * 16 * NPIX + mo);
    bf16x8 bb[2];
#pragma unroll
    for (int f = 0; f < 2; ++f) {
      const float* aq = ap + (size_t)f * 16 * NPIX + mo;
      float4 x = *reinterpret_cast<const float4*>(aq);
      float4 y = *reinterpret_cast<const float4*>(aq + 4);
      bf16x8 t;
      t[0] = (__bf16)x.x; t[1] = (__bf16)x.y; t[2] = (__bf16)x.z; t[3] = (__bf16)x.w;
      t[4] = (__bf16)y.x; t[5] = (__bf16)y.y; t[6] = (__bf16)y.z; t[7] = (__bf16)y.w;
      bb[f] = t;
    }
#pragma unroll
    for (int fr = 0; fr < 8; ++fr) {
      acc[fr][0] = __builtin_amdgcn_mfma_f32_16x16x32_bf16(a[fr], bb[0], acc[fr][0], 0, 0, 0);
      acc[fr][1] = __builtin_amdgcn_mfma_f32_16x16x32_bf16(a[fr], bb[1], acc[fr][1], 0, 0, 0);
    }
  }

  const int cg = (l >> 4) * 4;
#pragma unroll
  for (int fr = 0; fr < 8; ++fr)
#pragma unroll
    for (int fc = 0; fc < 2; ++fc)
#pragma unroll
      for (int r = 0; r < 4; ++r) {
        const int c = wr * 128 + fr * 16 + cg + r;
        const int n = n0 + wc * 32 + fc * 16 + rl;
        out[((size_t)b * CCH + c) * NPIX + n] = acc[fr][fc][r];
      }
}

extern "C" void kernel_launch(void* const* d_in, const int* in_sizes, int n_in,
                              void* d_out, int out_size, void* d_ws, size_t ws_size,
                              hipStream_t stream)
{
  const float* p  = (const float*)d_in[0];
  const float* bi = (const float*)d_in[1];
  const float* Wq = (const float*)d_in[2];
  const float* bq = (const float*)d_in[3];
  const float* Wk = (const float*)d_in[4];
  const float* bk = (const float*)d_in[5];

  float* out  = (float*)d_out;                       // [8][256][4096]
  float* attn = out + (size_t)BATCH * CCH * NPIX;    // [8][4096][4096]

  const size_t QK = (size_t)BATCH * NPIX * COO;      // 4,194,304 elems
  __bf16* qhi = (__bf16*)d_ws;
  __bf16* qlo = qhi + QK;
  __bf16* khi = qlo + QK;
  __bf16* klo = khi + QK;
  __bf16* Vb  = klo + QK;                            // 8,388,608 elems
  // total ws use: 50,331,648 bytes

  proj_kernel<<<dim3(4, 8, 8), 256, 0, stream>>>(p,  Wq, bq, qhi, qlo);
  proj_kernel<<<dim3(4, 8, 8), 256, 0, stream>>>(bi, Wk, bk, khi, klo);
  cvt_bf16_kernel<<<4096, 256, 0, stream>>>(bi, Vb, 1048576);
  energy_kernel<<<dim3(32, 32, 8), 256, 0, stream>>>(qhi, qlo, khi, klo, attn);
  softmax_kernel<<<32768, 256, 0, stream>>>(attn);
  pv_kernel<<<dim3(64, 1, 8), 256, 0, stream>>>(Vb, attn, out);
}

// Round 2
// 838.554 us; speedup vs baseline: 1.2016x; 1.2016x over previous
//
#include <hip/hip_runtime.h>
#include <hip/hip_bf16.h>
#include <cstdint>

// SpatialAttention: B=8, C=256, CO=128, H=W=64, N=4096
//   q = Wq@p + bq   [B,N,CO]
//   k = Wk@b + bk   [B,N,CO]
//   e = q k^T       [B,N,N]   (K=CO=128)  -- split-bf16 MFMA (fp32-accurate)
//   attn = softmax(e, -1)      (output 1)
//   out = attn @ b^T [B,C,N]   (output 0) -- bf16 MFMA
//
// d_ws (preferred layout, 318,767,104 B):
//   attnb [8*4096*4096] bf16 (268MB), qhi/qlo/khi/klo 4x[8*4096*128] bf16,
//   Vb [8*256*4096] bf16.
// Fallback (ws < that): round-1 layout, f32-attn pv.

#define BATCH 8
#define CCH   256
#define COO   128
#define NPIX  4096

typedef __bf16 bf16x8 __attribute__((ext_vector_type(8)));
typedef __bf16 bf16x4 __attribute__((ext_vector_type(4)));
typedef float  f32x4  __attribute__((ext_vector_type(4)));

__device__ __forceinline__ void gload16(const void* g, void* l) {
  __builtin_amdgcn_global_load_lds(
      (const __attribute__((address_space(1))) uint32_t*)g,
      (__attribute__((address_space(3))) uint32_t*)l, 16, 0, 0);
}

// ---------------- K1: projection, fp32 compute, bf16 hi/lo split output [B][N][CO]
__global__ __launch_bounds__(256) void proj_kernel(
    const float* __restrict__ X,    // [B][C][N]
    const float* __restrict__ W,    // [CO][C]
    const float* __restrict__ bias, // [CO]
    __bf16* __restrict__ out_hi,    // [B][N][CO]
    __bf16* __restrict__ out_lo)
{
  __shared__ float wlds[16][256];
  __shared__ float blds[16];
  const int b   = blockIdx.z;
  const int o0  = blockIdx.y * 16;
  const int n0  = blockIdx.x * 1024;
  const int tid = threadIdx.x;

  for (int i = tid; i < 16 * 256; i += 256)
    wlds[i >> 8][i & 255] = W[(size_t)(o0 + (i >> 8)) * CCH + (i & 255)];
  if (tid < 16) blds[tid] = bias[o0 + tid];
  __syncthreads();

  const int n = n0 + tid * 4;
  const float* xp = X + ((size_t)b * CCH) * NPIX + n;

  float acc[16][4];
#pragma unroll
  for (int o = 0; o < 16; ++o)
#pragma unroll
    for (int j = 0; j < 4; ++j) acc[o][j] = 0.f;

  for (int c4 = 0; c4 < CCH; c4 += 4) {
    float pvv[4][4];
#pragma unroll
    for (int cc = 0; cc < 4; ++cc) {
      float4 t = *reinterpret_cast<const float4*>(xp + (size_t)(c4 + cc) * NPIX);
      pvv[cc][0] = t.x; pvv[cc][1] = t.y; pvv[cc][2] = t.z; pvv[cc][3] = t.w;
    }
#pragma unroll
    for (int o = 0; o < 16; ++o) {
      float4 wv = *reinterpret_cast<const float4*>(&wlds[o][c4]);
      float wa[4] = {wv.x, wv.y, wv.z, wv.w};
#pragma unroll
      for (int cc = 0; cc < 4; ++cc)
#pragma unroll
        for (int j = 0; j < 4; ++j)
          acc[o][j] += wa[cc] * pvv[cc][j];
    }
  }

#pragma unroll
  for (int j = 0; j < 4; ++j) {
    const size_t base = ((size_t)b * NPIX + n + j) * COO + o0;
    bf16x8 hv[2], lv[2];
#pragma unroll
    for (int o = 0; o < 16; ++o) {
      float v = acc[o][j] + blds[o];
      __bf16 h = (__bf16)v;
      float  r = v - (float)h;
      hv[o >> 3][o & 7] = h;
      lv[o >> 3][o & 7] = (__bf16)r;
    }
    *reinterpret_cast<bf16x8*>(out_hi + base)     = hv[0];
    *reinterpret_cast<bf16x8*>(out_hi + base + 8) = hv[1];
    *reinterpret_cast<bf16x8*>(out_lo + base)     = lv[0];
    *reinterpret_cast<bf16x8*>(out_lo + base + 8) = lv[1];
  }
}

// ---------------- K1b: f32 -> bf16 elementwise (V copy)
__global__ __launch_bounds__(256) void cvt_bf16_kernel(
    const float* __restrict__ in, __bf16* __restrict__ outp, int n8)
{
  const int idx = blockIdx.x * 256 + threadIdx.x;
  if (idx >= n8) return;
  const float* ip = in + (size_t)idx * 8;
  float4 x = *reinterpret_cast<const float4*>(ip);
  float4 y = *reinterpret_cast<const float4*>(ip + 4);
  bf16x8 t;
  t[0] = (__bf16)x.x; t[1] = (__bf16)x.y; t[2] = (__bf16)x.z; t[3] = (__bf16)x.w;
  t[4] = (__bf16)y.x; t[5] = (__bf16)y.y; t[6] = (__bf16)y.z; t[7] = (__bf16)y.w;
  *reinterpret_cast<bf16x8*>(outp + (size_t)idx * 8) = t;
}

// ---------------- K2: energy e[n,m] = sum_o q[n,o]*k[m,o], split-bf16
__global__ __launch_bounds__(256) void energy_kernel(
    const __bf16* __restrict__ qhip, const __bf16* __restrict__ qlop,
    const __bf16* __restrict__ khip, const __bf16* __restrict__ klop,
    float* __restrict__ eout)
{
  const int b   = blockIdx.z;
  const int m0  = blockIdx.x * 128;
  const int n0  = blockIdx.y * 128;
  const int tid = threadIdx.x;
  const int w = tid >> 6, l = tid & 63;
  const int wr = w >> 1, wc = w & 1;
  const int rl = l & 15;
  const int k8 = (l >> 4) * 8;

  const size_t qrow = ((size_t)b * NPIX + n0 + wr * 64 + rl) * COO + k8;
  const size_t krow = ((size_t)b * NPIX + m0 + wc * 64 + rl) * COO + k8;
  const __bf16* qhp = qhip + qrow;
  const __bf16* qlp = qlop + qrow;
  const __bf16* khp = khip + krow;
  const __bf16* klp = klop + krow;

  f32x4 zero = {0.f, 0.f, 0.f, 0.f};
  f32x4 acc[4][4];
#pragma unroll
  for (int fr = 0; fr < 4; ++fr)
#pragma unroll
    for (int fc = 0; fc < 4; ++fc) acc[fr][fc] = zero;

#pragma unroll
  for (int ks = 0; ks < 4; ++ks) {
    const int ko = ks * 32;
    bf16x8 ah[4], al[4], bh[4], bl[4];
#pragma unroll
    for (int f = 0; f < 4; ++f) {
      const size_t off = (size_t)f * 16 * COO + ko;
      ah[f] = *reinterpret_cast<const bf16x8*>(qhp + off);
      al[f] = *reinterpret_cast<const bf16x8*>(qlp + off);
      bh[f] = *reinterpret_cast<const bf16x8*>(khp + off);
      bl[f] = *reinterpret_cast<const bf16x8*>(klp + off);
    }
#pragma unroll
    for (int fr = 0; fr < 4; ++fr)
#pragma unroll
      for (int fc = 0; fc < 4; ++fc) {
        acc[fr][fc] = __builtin_amdgcn_mfma_f32_16x16x32_bf16(ah[fr], bh[fc], acc[fr][fc], 0, 0, 0);
        acc[fr][fc] = __builtin_amdgcn_mfma_f32_16x16x32_bf16(ah[fr], bl[fc], acc[fr][fc], 0, 0, 0);
        acc[fr][fc] = __builtin_amdgcn_mfma_f32_16x16x32_bf16(al[fr], bh[fc], acc[fr][fc], 0, 0, 0);
      }
  }

  const int cg = (l >> 4) * 4;
#pragma unroll
  for (int fr = 0; fr < 4; ++fr)
#pragma unroll
    for (int r = 0; r < 4; ++r) {
      const int row = n0 + wr * 64 + fr * 16 + cg + r;
      float* op = eout + ((size_t)b * NPIX + row) * NPIX + m0 + wc * 64 + rl;
#pragma unroll
      for (int fc = 0; fc < 4; ++fc)
        op[fc * 16] = acc[fr][fc][r];
    }
}

// ---------------- K3: row softmax in place; optional bf16 copy to ws
template <bool WRITE_BF16>
__global__ __launch_bounds__(256) void softmax_kernel(
    float* __restrict__ attn, __bf16* __restrict__ attnb)
{
  const size_t row = blockIdx.x;
  float* p = attn + row * NPIX;
  const int tid = threadIdx.x;
  const int w = tid >> 6, l = tid & 63;

  float4 v[4];
#pragma unroll
  for (int j = 0; j < 4; ++j)
    v[j] = *reinterpret_cast<const float4*>(p + j * 1024 + tid * 4);

  float m = -1e30f;
#pragma unroll
  for (int j = 0; j < 4; ++j)
    m = fmaxf(m, fmaxf(fmaxf(v[j].x, v[j].y), fmaxf(v[j].z, v[j].w)));
#pragma unroll
  for (int off = 32; off; off >>= 1) m = fmaxf(m, __shfl_xor(m, off));

  __shared__ float smax[4];
  __shared__ float ssum[4];
  if (l == 0) smax[w] = m;
  __syncthreads();
  m = fmaxf(fmaxf(smax[0], smax[1]), fmaxf(smax[2], smax[3]));

  float s = 0.f;
#pragma unroll
  for (int j = 0; j < 4; ++j) {
    v[j].x = __expf(v[j].x - m); s += v[j].x;
    v[j].y = __expf(v[j].y - m); s += v[j].y;
    v[j].z = __expf(v[j].z - m); s += v[j].z;
    v[j].w = __expf(v[j].w - m); s += v[j].w;
  }
#pragma unroll
  for (int off = 32; off; off >>= 1) s += __shfl_xor(s, off);
  if (l == 0) ssum[w] = s;
  __syncthreads();
  s = ssum[0] + ssum[1] + ssum[2] + ssum[3];
  const float inv = 1.0f / s;

#pragma unroll
  for (int j = 0; j < 4; ++j) {
    v[j].x *= inv; v[j].y *= inv; v[j].z *= inv; v[j].w *= inv;
    *reinterpret_cast<float4*>(p + j * 1024 + tid * 4) = v[j];
    if (WRITE_BF16) {
      bf16x4 t;
      t[0] = (__bf16)v[j].x; t[1] = (__bf16)v[j].y;
      t[2] = (__bf16)v[j].z; t[3] = (__bf16)v[j].w;
      *reinterpret_cast<bf16x4*>(attnb + row * NPIX + j * 1024 + tid * 4) = t;
    }
  }
}

// ---------------- K4 (new): LDS-staged PV GEMM, bf16 attn input
// per WG: 128c x 64n tile, m-loop in steps of 64. grid (64, 2, 8).
__global__ __launch_bounds__(256) void pv2_kernel(
    const __bf16* __restrict__ V,   // [B][C][M] bf16
    const __bf16* __restrict__ An,  // [B][N][M] bf16 (softmaxed)
    float* __restrict__ out)        // [B][C][N]
{
  // per buffer: Vt 128x64 bf16 (16KB) + At 64x64 bf16 (8KB) = 24KB; x2 dbuf
  __shared__ __bf16 lds[2 * 12288];
  const int b   = blockIdx.z;
  const int c0  = blockIdx.y * 128;
  const int n0  = blockIdx.x * 64;
  const int tid = threadIdx.x;
  const int w = tid >> 6, l = tid & 63;
  const int wr = w >> 1, wc = w & 1;
  const int rl = l & 15, k8 = (l >> 4) * 8;

  const uint8_t* Vbase = (const uint8_t*)(V + ((size_t)b * CCH + c0) * NPIX);
  const uint8_t* Abase = (const uint8_t*)(An + ((size_t)b * NPIX + n0) * NPIX);
  uint8_t* ldsb = (uint8_t*)lds;

  f32x4 zero = {0.f, 0.f, 0.f, 0.f};
  f32x4 acc[4][2];
#pragma unroll
  for (int fr = 0; fr < 4; ++fr) { acc[fr][0] = zero; acc[fr][1] = zero; }

  // stage one 24KB buffer (both tiles) for m-tile t0; source pre-swizzled so
  // LDS holds [row][col ^ ((row&7)<<4)] at byte granularity 16 (rule #21).
#define STAGE(buf, t0)                                                        \
  {                                                                           \
    const int t0b = (t0) * 128;                                               \
    _Pragma("unroll")                                                         \
    for (int q = 0; q < 6; ++q) {                                             \
      const int g = q * 4 + w;                                                \
      const int byteD = g * 1024 + l * 16;                                    \
      if (g < 16) {                                                           \
        const int row = byteD >> 7, colb = byteD & 127;                       \
        const int cs = colb ^ ((row & 7) << 4);                               \
        gload16(Vbase + (size_t)row * 8192 + t0b + cs,                        \
                ldsb + (buf) * 24576 + g * 1024);                             \
      } else {                                                                \
        const int byteA = byteD - 16384;                                      \
        const int row = byteA >> 7, colb = byteA & 127;                       \
        const int cs = colb ^ ((row & 7) << 4);                               \
        gload16(Abase + (size_t)row * 8192 + t0b + cs,                        \
                ldsb + (buf) * 24576 + g * 1024);                             \
      }                                                                       \
    }                                                                         \
  }

  STAGE(0, 0);
  __syncthreads();

  for (int t = 0; t < 64; ++t) {
    const int cur = t & 1;
    if (t + 1 < 64) STAGE(cur ^ 1, t + 1);
    const uint8_t* Vt = ldsb + cur * 24576;
    const uint8_t* At = Vt + 16384;
#pragma unroll
    for (int ks = 0; ks < 2; ++ks) {
      const int colb = k8 * 2 + ks * 64;
      bf16x8 a[4], bb[2];
#pragma unroll
      for (int f = 0; f < 4; ++f) {
        const int row = wr * 64 + f * 16 + rl;
        a[f] = *reinterpret_cast<const bf16x8*>(
            Vt + row * 128 + (colb ^ ((row & 7) << 4)));
      }
#pragma unroll
      for (int f = 0; f < 2; ++f) {
        const int row = wc * 32 + f * 16 + rl;
        bb[f] = *reinterpret_cast<const bf16x8*>(
            At + row * 128 + (colb ^ ((row & 7) << 4)));
      }
#pragma unroll
      for (int fr = 0; fr < 4; ++fr) {
        acc[fr][0] = __builtin_amdgcn_mfma_f32_16x16x32_bf16(a[fr], bb[0], acc[fr][0], 0, 0, 0);
        acc[fr][1] = __builtin_amdgcn_mfma_f32_16x16x32_bf16(a[fr], bb[1], acc[fr][1], 0, 0, 0);
      }
    }
    __syncthreads();
  }
#undef STAGE

  const int cg = (l >> 4) * 4;
#pragma unroll
  for (int fr = 0; fr < 4; ++fr)
#pragma unroll
    for (int fc = 0; fc < 2; ++fc)
#pragma unroll
      for (int r = 0; r < 4; ++r) {
        const int c = c0 + wr * 64 + fr * 16 + cg + r;
        const int n = n0 + wc * 32 + fc * 16 + rl;
        out[((size_t)b * CCH + c) * NPIX + n] = acc[fr][fc][r];
      }
}

// ---------------- K4 (fallback): round-1 pv, f32 attn direct
__global__ __launch_bounds__(256) void pv_kernel(
    const __bf16* __restrict__ V,    // [B][C][M] bf16
    const float*  __restrict__ attn, // [B][N][M] f32
    float* __restrict__ out)         // [B][C][N]
{
  const int b   = blockIdx.z;
  const int n0  = blockIdx.x * 64;
  const int tid = threadIdx.x;
  const int w = tid >> 6, l = tid & 63;
  const int wr = w >> 1, wc = w & 1;
  const int rl = l & 15, k8 = (l >> 4) * 8;

  const __bf16* vp = V + ((size_t)b * CCH + wr * 128 + rl) * NPIX + k8;
  const float*  ap = attn + ((size_t)b * NPIX + n0 + wc * 32 + rl) * NPIX + k8;

  f32x4 zero = {0.f, 0.f, 0.f, 0.f};
  f32x4 acc[8][2];
#pragma unroll
  for (int fr = 0; fr < 8; ++fr) { acc[fr][0] = zero; acc[fr][1] = zero; }

  for (int ks = 0; ks < 128; ++ks) {
    const int mo = ks * 32;
    bf16x8 a[8];
#pragma unroll
    for (int f = 0; f < 8; ++f)
      a[f] = *reinterpret_cast<const bf16x8*>(vp + (size_t)f * 16 * NPIX + mo);
    bf16x8 bb[2];
#pragma unroll
    for (int f = 0; f < 2; ++f) {
      const float* aq = ap + (size_t)f * 16 * NPIX + mo;
      float4 x = *reinterpret_cast<const float4*>(aq);
      float4 y = *reinterpret_cast<const float4*>(aq + 4);
      bf16x8 t;
      t[0] = (__bf16)x.x; t[1] = (__bf16)x.y; t[2] = (__bf16)x.z; t[3] = (__bf16)x.w;
      t[4] = (__bf16)y.x; t[5] = (__bf16)y.y; t[6] = (__bf16)y.z; t[7] = (__bf16)y.w;
      bb[f] = t;
    }
#pragma unroll
    for (int fr = 0; fr < 8; ++fr) {
      acc[fr][0] = __builtin_amdgcn_mfma_f32_16x16x32_bf16(a[fr], bb[0], acc[fr][0], 0, 0, 0);
      acc[fr][1] = __builtin_amdgcn_mfma_f32_16x16x32_bf16(a[fr], bb[1], acc[fr][1], 0, 0, 0);
    }
  }

  const int cg = (l >> 4) * 4;
#pragma unroll
  for (int fr = 0; fr < 8; ++fr)
#pragma unroll
    for (int fc = 0; fc < 2; ++fc)
#pragma unroll
      for (int r = 0; r < 4; ++r) {
        const int c = wr * 128 + fr * 16 + cg + r;
        const int n = n0 + wc * 32 + fc * 16 + rl;
        out[((size_t)b * CCH + c) * NPIX + n] = acc[fr][fc][r];
      }
}

extern "C" void kernel_launch(void* const* d_in, const int* in_sizes, int n_in,
                              void* d_out, int out_size, void* d_ws, size_t ws_size,
                              hipStream_t stream)
{
  const float* p  = (const float*)d_in[0];
  const float* bi = (const float*)d_in[1];
  const float* Wq = (const float*)d_in[2];
  const float* bq = (const float*)d_in[3];
  const float* Wk = (const float*)d_in[4];
  const float* bk = (const float*)d_in[5];

  float* out  = (float*)d_out;                       // [8][256][4096]
  float* attn = out + (size_t)BATCH * CCH * NPIX;    // [8][4096][4096]

  const size_t QK  = (size_t)BATCH * NPIX * COO;     // 4,194,304 elems
  const size_t VB  = (size_t)BATCH * CCH * NPIX;     // 8,388,608 elems
  const size_t ANB = (size_t)BATCH * NPIX * NPIX;    // 134,217,728 elems
  const size_t need_bf16 = (ANB + 4 * QK + VB) * 2;  // 318,767,104 B

  if (ws_size >= need_bf16) {
    __bf16* attnb = (__bf16*)d_ws;
    __bf16* qhi = attnb + ANB;
    __bf16* qlo = qhi + QK;
    __bf16* khi = qlo + QK;
    __bf16* klo = khi + QK;
    __bf16* Vb  = klo + QK;

    proj_kernel<<<dim3(4, 8, 8), 256, 0, stream>>>(p,  Wq, bq, qhi, qlo);
    proj_kernel<<<dim3(4, 8, 8), 256, 0, stream>>>(bi, Wk, bk, khi, klo);
    cvt_bf16_kernel<<<4096, 256, 0, stream>>>(bi, Vb, 1048576);
    energy_kernel<<<dim3(32, 32, 8), 256, 0, stream>>>(qhi, qlo, khi, klo, attn);
    softmax_kernel<true><<<32768, 256, 0, stream>>>(attn, attnb);
    pv2_kernel<<<dim3(64, 2, 8), 256, 0, stream>>>(Vb, attnb, out);
  } else {
    __bf16* qhi = (__bf16*)d_ws;
    __bf16* qlo = qhi + QK;
    __bf16* khi = qlo + QK;
    __bf16* klo = khi + QK;
    __bf16* Vb  = klo + QK;

    proj_kernel<<<dim3(4, 8, 8), 256, 0, stream>>>(p,  Wq, bq, qhi, qlo);
    proj_kernel<<<dim3(4, 8, 8), 256, 0, stream>>>(bi, Wk, bk, khi, klo);
    cvt_bf16_kernel<<<4096, 256, 0, stream>>>(bi, Vb, 1048576);
    energy_kernel<<<dim3(32, 32, 8), 256, 0, stream>>>(qhi, qlo, khi, klo, attn);
    softmax_kernel<false><<<32768, 256, 0, stream>>>(attn, nullptr);
    pv_kernel<<<dim3(64, 1, 8), 256, 0, stream>>>(Vb, attn, out);
  }
}